// Round 3
// baseline (472.964 us; speedup 1.0000x reference)
//
#include <hip/hip_runtime.h>
#include <math.h>

// BoxDecoder R8: persistent wave-autonomous kernel. No __syncthreads anywhere.
//
// Evidence so far: R6 (nt stores) == R7 (plain stores) == ~190us kernel-
// attributable vs ~90us mixed-stream roofline, while the harness fill proves
// 6.3 TB/s on this buffer. Store path exonerated by the R6/R7 A/B. Remaining
// suspect: per-block latency chain (HBM load -> __syncthreads -> stores ->
// block exit) x 25K short-lived blocks = bursty store issue + launch churn.
//
// R8: one WAVE owns each 64-t chunk; LDS slab is wave-private so the
// load->broadcast->store handoff needs only in-order per-wave DS semantics
// (+ explicit s_waitcnt lgkmcnt(0), belt and suspenders; wave64 lockstep
// makes cross-lane LDS exchange barrier-free). Grid-stride persistent loop
// (2048 blocks * 4 waves, ~3 chunks/wave) removes block churn; waves issue
// loads for chunk k+1's iteration immediately after chunk k's stores with no
// inter-wave coupling. Loads are plain (L2-allocating) again.
//
// Output layout (verified R1-R7): box_tensor [rows,6] floats, then mask
// [rows], then batch_index [rows]; rows = B*A*C, row = t*C + c.
// Per t (C==8): 48 floats = 12 float4s; lg in [0,12) per t: s=lg%12/3, jm=%3:
//   jm0 -> (x1,y1,x2,y2)        of row 2s
//   jm1 -> (score[2s], 2s+1, x1, y1)
//   jm2 -> (x2, y2, score[2s+1], 2s+2)
// mask/bidx: 2 float4 per t, float4 i covers rows 4i..4i+3 (same t = i/2).
//
// Magic divide m=floor(2^38/A)+1 exact for n<=1.6M (verified R1-R3).

#define MAGIC_SHIFT 38

typedef float vfloat4 __attribute__((ext_vector_type(4)));

__global__ __launch_bounds__(256) void box_decode_pers(
    const vfloat4* __restrict__ anchors,  // [A] (cx, cy, w, h)
    const vfloat4* __restrict__ loc,      // [nT]
    const vfloat4* __restrict__ cls4,     // [nT*2]  (C==8)
    const float*   __restrict__ varx_p,
    const float*   __restrict__ vary_p,
    const float*   __restrict__ th_p,
    vfloat4*       __restrict__ out_box4, // [nT*12]
    vfloat4*       __restrict__ out_mask4,// [nT*2]
    vfloat4*       __restrict__ out_bidx4,// [nT*2]
    unsigned nChunks, unsigned nT, unsigned A,
    unsigned long long invA)              // floor(2^38/A)+1
{
    __shared__ vfloat4 s_box[4][64];      // wave-private: box per t
    __shared__ vfloat4 s_cls[4][128];     // wave-private: 512 scores

    const unsigned wv   = threadIdx.x >> 6;
    const unsigned lane = threadIdx.x & 63u;
    vfloat4* sbox  = s_box[wv];
    vfloat4* scls4 = s_cls[wv];
    const float* scls = (const float*)scls4;

    const float varx = *varx_p;
    const float vary = *vary_p;
    const float th   = *th_p;

    const unsigned gw = blockIdx.x * 4u + wv;   // global wave id
    const unsigned nw = gridDim.x * 4u;         // total waves

    for (unsigned ch = gw; ch < nChunks; ch += nw) {
        const unsigned t0     = ch * 64u;
        const unsigned nt_blk = (nT - t0 < 64u) ? (nT - t0) : 64u;

        // ---- phase 1: decode own t -> wave-private LDS ------------------
        if (lane < nt_blk) {
            unsigned t = t0 + lane;
            unsigned b = (unsigned)(((unsigned long long)t * invA) >> MAGIC_SHIFT);
            unsigned a = t - b * A;
            vfloat4 anc = anchors[a];        // reused across b: L2-cached
            vfloat4 lp  = loc[t];
            float x = fmaf(lp.x * varx, anc.z, anc.x);
            float y = fmaf(lp.y * varx, anc.w, anc.y);
            float w = expf(lp.z * vary) * anc.z;
            float h = expf(lp.w * vary) * anc.w;
            vfloat4 bx;
            bx.x = fmaf(w, -0.5f, x);
            bx.y = fmaf(h, -0.5f, y);
            bx.z = fmaf(w,  0.5f, x);
            bx.w = fmaf(h,  0.5f, y);
            sbox[lane] = bx;
        }

        // ---- phase 2: cls -> LDS; mask + bidx stores (dense float4) -----
        const unsigned cbase = t0 * 2u;
        const unsigned clim  = nt_blk * 2u;
        if (lane < clim) {
            vfloat4 c = cls4[cbase + lane];
            scls4[lane] = c;
            vfloat4 m;
            m.x = (c.x >= th) ? 1.0f : 0.0f;
            m.y = (c.y >= th) ? 1.0f : 0.0f;
            m.z = (c.z >= th) ? 1.0f : 0.0f;
            m.w = (c.w >= th) ? 1.0f : 0.0f;
            out_mask4[cbase + lane] = m;
            unsigned tm = t0 + (lane >> 1);
            unsigned bm = (unsigned)(((unsigned long long)tm * invA) >> MAGIC_SHIFT);
            float bf = (float)bm;
            vfloat4 bb = {bf, bf, bf, bf};
            out_bidx4[cbase + lane] = bb;
        }
        {
            unsigned l2 = lane + 64u;
            if (l2 < clim) {
                vfloat4 c = cls4[cbase + l2];
                scls4[l2] = c;
                vfloat4 m;
                m.x = (c.x >= th) ? 1.0f : 0.0f;
                m.y = (c.y >= th) ? 1.0f : 0.0f;
                m.z = (c.z >= th) ? 1.0f : 0.0f;
                m.w = (c.w >= th) ? 1.0f : 0.0f;
                out_mask4[cbase + l2] = m;
                unsigned tm = t0 + 32u + (lane >> 1);
                unsigned bm = (unsigned)(((unsigned long long)tm * invA) >> MAGIC_SHIFT);
                float bf = (float)bm;
                vfloat4 bb = {bf, bf, bf, bf};
                out_bidx4[cbase + l2] = bb;
            }
        }

        // all wave-private LDS writes retired before cross-lane reads
        asm volatile("s_waitcnt lgkmcnt(0)" ::: "memory");

        // ---- phase 3: 768 box float4s, dense & coalesced ----------------
        const unsigned lim  = nt_blk * 12u;
        const unsigned base = t0 * 12u;
#pragma unroll
        for (unsigned k = 0u; k < 12u; ++k) {
            unsigned lg = k * 64u + lane;          // 0..767
            if (lg < lim) {
                unsigned lt = lg / 12u;            // const-div -> magic
                unsigned j  = lg - lt * 12u;
                unsigned s  = j / 3u;
                unsigned jm = j - s * 3u;
                vfloat4 bx  = sbox[lt];            // few distinct addrs: broadcast
                float sc0 = scls[lt * 8u + 2u * s];
                float sc1 = scls[lt * 8u + 2u * s + 1u];
                float l0  = (float)(2u * s + 1u);
                float l1  = (float)(2u * s + 2u);
                bool j0 = (jm == 0u);
                bool j1 = (jm == 1u);
                vfloat4 r;
                r.x = j0 ? bx.x : (j1 ? sc0  : bx.z);
                r.y = j0 ? bx.y : (j1 ? l0   : bx.w);
                r.z = j0 ? bx.z : (j1 ? bx.x : sc1);
                r.w = j0 ? bx.w : (j1 ? bx.y : l1);
                out_box4[base + lg] = r;
            }
        }
    }
}

// ---------------- Generic fallback (any C with (6C)%4==0) ---------------
__global__ __launch_bounds__(256) void box_decode_kernel(
    const float4* __restrict__ anchors,
    const float4* __restrict__ loc,
    const float*  __restrict__ cls,
    const float*  __restrict__ varx_p,
    const float*  __restrict__ vary_p,
    const float*  __restrict__ th_p,
    vfloat4*      __restrict__ out_box4,
    float*        __restrict__ out_mask,
    float*        __restrict__ out_bidx,
    unsigned n4, unsigned A, unsigned C, unsigned f4_per_t,
    unsigned long long invA, unsigned long long invF)
{
    unsigned g = blockIdx.x * 256u + threadIdx.x;
    if (g >= n4) return;
    unsigned t  = (unsigned)(((unsigned long long)g * invF) >> MAGIC_SHIFT);
    unsigned j  = g - t * f4_per_t;
    unsigned b  = (unsigned)(((unsigned long long)t * invA) >> MAGIC_SHIFT);
    unsigned a  = t - b * A;
    unsigned s  = j / 3u;
    unsigned jm = j - s * 3u;
    float varx = *varx_p, vary = *vary_p, th = *th_p;
    float4 anc = anchors[a];
    float4 lp  = loc[t];
    float x = fmaf(lp.x * varx, anc.z, anc.x);
    float y = fmaf(lp.y * varx, anc.w, anc.y);
    float w = expf(lp.z * vary) * anc.z;
    float h = expf(lp.w * vary) * anc.w;
    float x1 = fmaf(w, -0.5f, x);
    float y1 = fmaf(h, -0.5f, y);
    float x2 = fmaf(w,  0.5f, x);
    float y2 = fmaf(h,  0.5f, y);
    unsigned r0 = t * C + 2u * s;
    float bf = (float)b;
    vfloat4 r;
    if (jm == 0u) {
        r.x = x1; r.y = y1; r.z = x2; r.w = y2;
    } else if (jm == 1u) {
        float sc0 = cls[r0];
        r.x = sc0; r.y = (float)(2u * s + 1u); r.z = x1; r.w = y1;
        out_mask[r0] = (sc0 >= th) ? 1.0f : 0.0f;
        out_bidx[r0] = bf;
    } else {
        float sc1 = cls[r0 + 1u];
        r.x = x2; r.y = y2; r.z = sc1; r.w = (float)(2u * s + 2u);
        out_mask[r0 + 1u] = (sc1 >= th) ? 1.0f : 0.0f;
        out_bidx[r0 + 1u] = bf;
    }
    out_box4[g] = r;
}

extern "C" void kernel_launch(void* const* d_in, const int* in_sizes, int n_in,
                              void* d_out, int out_size, void* d_ws, size_t ws_size,
                              hipStream_t stream) {
    const float* anchors = (const float*)d_in[0];
    const float* loc     = (const float*)d_in[1];
    const float* cls     = (const float*)d_in[2];
    const float* varx_p  = (const float*)d_in[3];
    const float* vary_p  = (const float*)d_in[4];
    const float* th_p    = (const float*)d_in[5];

    unsigned A = (unsigned)(in_sizes[0] / 4);
    unsigned B = (unsigned)((unsigned)in_sizes[1] / (4u * A));
    unsigned C = (unsigned)((unsigned)in_sizes[2] / (A * B));
    unsigned nT = B * A;
    unsigned rows = nT * C;

    float* out_box  = (float*)d_out;
    float* out_mask = out_box + (size_t)rows * 6;
    float* out_bidx = out_mask + rows;

    unsigned long long invA = ((1ULL << MAGIC_SHIFT) / A) + 1ULL;

    if (C == 8u) {
        unsigned nChunks = (nT + 63u) / 64u;          // 25,000 for this shape
        unsigned nb = (nChunks + 3u) / 4u;            // 1 wave per chunk
        if (nb > 2048u) nb = 2048u;                   // persistent grid, 8 blk/CU
        box_decode_pers<<<dim3(nb), dim3(256), 0, stream>>>(
            (const vfloat4*)anchors, (const vfloat4*)loc, (const vfloat4*)cls,
            varx_p, vary_p, th_p,
            (vfloat4*)out_box, (vfloat4*)out_mask, (vfloat4*)out_bidx,
            nChunks, nT, A, invA);
    } else {
        unsigned f4_per_t = (6u * C) / 4u;
        unsigned n4 = rows * 6u / 4u;
        unsigned long long invF = ((1ULL << MAGIC_SHIFT) / f4_per_t) + 1ULL;
        unsigned nb = (n4 + 255u) / 256u;
        box_decode_kernel<<<dim3(nb), dim3(256), 0, stream>>>(
            (const float4*)anchors, (const float4*)loc, cls,
            varx_p, vary_p, th_p,
            (vfloat4*)out_box, out_mask, out_bidx,
            n4, A, C, f4_per_t, invA, invF);
    }
}